// Round 4
// baseline (101.737 us; speedup 1.0000x reference)
//
#include <hip/hip_runtime.h>

// Problem constants (fixed by setup_inputs).
constexpr int L  = 512;   // sequence length
constexpr int CS = 384;   // c_s
constexpr int CH = 32;    // c_h
constexpr int CZ = 128;   // c_z
constexpr float LN_EPS = 1e-5f;

// ---------------------------------------------------------------------------
// Kernel 1: LayerNorm over c_s + dual projection (w1/b1, w2/b2) + mask.
// Writes a[512][32] and b[512][32] fp32 into workspace.
// block = 256 (4 waves), each wave handles one row; grid = L/4 = 128.
// ---------------------------------------------------------------------------
__global__ __launch_bounds__(256) void k_ln_proj(
    const float* __restrict__ s, const int* __restrict__ mask,
    const float* __restrict__ ln_scale, const float* __restrict__ ln_bias,
    const float* __restrict__ w1, const float* __restrict__ b1,
    const float* __restrict__ w2, const float* __restrict__ b2,
    float* __restrict__ a, float* __restrict__ b)
{
    __shared__ float sn_lds[4][CS];
    const int wave = threadIdx.x >> 6;
    const int lane = threadIdx.x & 63;
    const int row  = blockIdx.x * 4 + wave;

    const float* srow = s + row * CS;
    float v[6];
    float sum = 0.f, sumsq = 0.f;
#pragma unroll
    for (int q = 0; q < 6; ++q) {
        v[q] = srow[lane + 64 * q];
        sum   += v[q];
        sumsq += v[q] * v[q];
    }
#pragma unroll
    for (int off = 32; off; off >>= 1) {
        sum   += __shfl_xor(sum, off);
        sumsq += __shfl_xor(sumsq, off);
    }
    const float mu   = sum * (1.f / CS);
    const float var  = sumsq * (1.f / CS) - mu * mu;
    const float rstd = rsqrtf(var + LN_EPS);
#pragma unroll
    for (int q = 0; q < 6; ++q) {
        const int k = lane + 64 * q;
        sn_lds[wave][k] = (v[q] - mu) * rstd * ln_scale[k] + ln_bias[k];
    }
    __syncthreads();

    // Projection: lanes 0..31 -> a (w1,b1); lanes 32..63 -> b (w2,b2).
    const int c    = lane & 31;
    const int half = lane >> 5;
    const float* W  = half ? w2 : w1;
    const float* Bv = half ? b2 : b1;
    float acc = 0.f;
#pragma unroll 4
    for (int k = 0; k < CS; ++k)
        acc += sn_lds[wave][k] * W[k * CH + c];
    const float m = (float)mask[row];
    const float outv = (acc + Bv[c]) * m;
    (half ? b : a)[row * CH + c] = outv;
}

// ---------------------------------------------------------------------------
// Kernel 2: T[j][c][z] = sum_e b[j][e] * w_out[(c*CH+e)*CZ + z]  (8 MB in ws).
// Spill-free layout: each thread owns ONE (c,z) pair -> w[32] loaded once
// (32 VGPRs), loops over a 64-row j-chunk staged in LDS.
// grid = 8 (c,z)-slices x 8 j-groups = 64 blocks x 512 threads.
// ---------------------------------------------------------------------------
__global__ __launch_bounds__(512) void k_T(
    const float* __restrict__ b, const float* __restrict__ w_out,
    float* __restrict__ T)
{
    const int czg = blockIdx.x & 7;    // (c,z) slice: 512 pairs
    const int jg  = blockIdx.x >> 3;   // j-chunk of 64
    const int t   = threadIdx.x;
    const int idx = czg * 512 + t;     // linear (c,z): c = idx>>7, z = idx&127
    const int c   = idx >> 7;
    const int z   = idx & (CZ - 1);

    float w[CH];
    const float* wp = w_out + (size_t)(c * CH) * CZ + z;
#pragma unroll
    for (int e = 0; e < CH; ++e) w[e] = wp[e * CZ];

    __shared__ float b_lds[64][CH];    // 8 KB
    ((float4*)b_lds)[t] = ((const float4*)(b + (size_t)jg * 64 * CH))[t];
    __syncthreads();

    float* Tp = T + (size_t)(jg * 64) * (CH * CZ) + idx;
#pragma unroll 4
    for (int jj = 0; jj < 64; ++jj) {
        float acc = 0.f;
#pragma unroll
        for (int e = 0; e < CH; ++e) acc += b_lds[jj][e] * w[e];
        Tp[(size_t)jj * (CH * CZ)] = acc;
    }
}

// ---------------------------------------------------------------------------
// Kernel 3: z[i,j,:] = a[i,:] @ T[j,:,:] + b_out.
// grid = 512: bj = bid & 63 (j-tile of 8), bi = bid >> 6 (i-tile of 64).
//   -> XCD x gets j-tiles {x, x+8, ...}: 1 MB of T per XCD, reused 8x.
// block = 512 (8 waves): wave owns j = j0 + wave, T[j] in 64 VGPRs (reused
// 64x); a-tile (8 KB) staged in LDS, rows read via uniform (broadcast)
// ds_read_b128. PLAIN stores (not nontemporal): L2 write-allocate is the
// high-BW drain path (fillBuffer proves 6.6 TB/s through L2); all 8 waves
// walk the same ii so stores cluster into 4 KB contiguous chunks for L2
// line aggregation.
// ---------------------------------------------------------------------------
__global__ __launch_bounds__(512) void k_main(
    const float* __restrict__ a, const float* __restrict__ T,
    const float* __restrict__ b_out, float* __restrict__ out)
{
    __shared__ float a_lds[64][CH];    // 8 KB

    const int bid = blockIdx.x;
    const int j0  = (bid & 63) * 8;
    const int i0  = (bid >> 6) * 64;
    const int t   = threadIdx.x;
    const int wave = t >> 6;
    const int lane = t & 63;
    const int j    = j0 + wave;

    // Stage a-tile: 2048 floats, 512 threads x float4.
    ((float4*)a_lds)[t] = ((const float4*)(a + (size_t)i0 * CH))[t];

    // T[j] column pair for this lane: 64 VGPRs.
    float2 T_reg[CH];
    const float* Tj = T + (size_t)j * (CH * CZ) + 2 * lane;
#pragma unroll
    for (int c = 0; c < CH; ++c)
        T_reg[c] = *(const float2*)(Tj + c * CZ);

    const float2 bo = *(const float2*)&b_out[2 * lane];
    float* outp = out + (size_t)i0 * L * CZ + (size_t)j * CZ + 2 * lane;

    __syncthreads();

#pragma unroll 2
    for (int ii = 0; ii < 64; ++ii) {
        const float4* ap = (const float4*)&a_lds[ii][0];
        float av[CH];
#pragma unroll
        for (int q = 0; q < 8; ++q) {
            const float4 tmp = ap[q];
            av[4 * q + 0] = tmp.x;
            av[4 * q + 1] = tmp.y;
            av[4 * q + 2] = tmp.z;
            av[4 * q + 3] = tmp.w;
        }
        float ax = 0.f, ay = 0.f;
#pragma unroll
        for (int c = 0; c < CH; ++c) {
            ax += av[c] * T_reg[c].x;
            ay += av[c] * T_reg[c].y;
        }
        float2 o;
        o.x = ax + bo.x;
        o.y = ay + bo.y;
        *(float2*)(outp + (size_t)ii * L * CZ) = o;
    }
}

// ---------------------------------------------------------------------------
extern "C" void kernel_launch(void* const* d_in, const int* in_sizes, int n_in,
                              void* d_out, int out_size, void* d_ws, size_t ws_size,
                              hipStream_t stream) {
    const float* s        = (const float*)d_in[0];
    const int*   mask     = (const int*)d_in[1];
    const float* ln_scale = (const float*)d_in[2];
    const float* ln_bias  = (const float*)d_in[3];
    const float* w1       = (const float*)d_in[4];
    const float* b1       = (const float*)d_in[5];
    const float* w2       = (const float*)d_in[6];
    const float* b2       = (const float*)d_in[7];
    const float* w_out    = (const float*)d_in[8];
    const float* b_out    = (const float*)d_in[9];
    float* out = (float*)d_out;

    // Workspace: a [512*32], b [512*32], T [512*32*128]  (8.125 MB total).
    float* a = (float*)d_ws;
    float* b = a + L * CH;
    float* T = b + L * CH;

    k_ln_proj<<<L / 4, 256, 0, stream>>>(s, mask, ln_scale, ln_bias,
                                         w1, b1, w2, b2, a, b);
    k_T<<<L / 8, 512, 0, stream>>>(b, w_out, T);
    k_main<<<512, 512, 0, stream>>>(a, T, b_out, out);
}

// Round 5
// 89.078 us; speedup vs baseline: 1.1421x; 1.1421x over previous
//
#include <hip/hip_runtime.h>

// Problem constants (fixed by setup_inputs).
constexpr int L  = 512;   // sequence length
constexpr int CS = 384;   // c_s
constexpr int CH = 32;    // c_h
constexpr int CZ = 128;   // c_z
constexpr float LN_EPS = 1e-5f;

typedef float f4 __attribute__((ext_vector_type(4)));

// ---------------------------------------------------------------------------
// Kernel 1: LayerNorm over c_s + dual projection (w1/b1, w2/b2) + mask.
// Writes a[512][32] and b[512][32] fp32 into workspace.
// ---------------------------------------------------------------------------
__global__ __launch_bounds__(256) void k_ln_proj(
    const float* __restrict__ s, const int* __restrict__ mask,
    const float* __restrict__ ln_scale, const float* __restrict__ ln_bias,
    const float* __restrict__ w1, const float* __restrict__ b1,
    const float* __restrict__ w2, const float* __restrict__ b2,
    float* __restrict__ a, float* __restrict__ b)
{
    __shared__ float sn_lds[4][CS];
    const int wave = threadIdx.x >> 6;
    const int lane = threadIdx.x & 63;
    const int row  = blockIdx.x * 4 + wave;

    const float* srow = s + row * CS;
    float v[6];
    float sum = 0.f, sumsq = 0.f;
#pragma unroll
    for (int q = 0; q < 6; ++q) {
        v[q] = srow[lane + 64 * q];
        sum   += v[q];
        sumsq += v[q] * v[q];
    }
#pragma unroll
    for (int off = 32; off; off >>= 1) {
        sum   += __shfl_xor(sum, off);
        sumsq += __shfl_xor(sumsq, off);
    }
    const float mu   = sum * (1.f / CS);
    const float var  = sumsq * (1.f / CS) - mu * mu;
    const float rstd = rsqrtf(var + LN_EPS);
#pragma unroll
    for (int q = 0; q < 6; ++q) {
        const int k = lane + 64 * q;
        sn_lds[wave][k] = (v[q] - mu) * rstd * ln_scale[k] + ln_bias[k];
    }
    __syncthreads();

    const int c    = lane & 31;
    const int half = lane >> 5;
    const float* W  = half ? w2 : w1;
    const float* Bv = half ? b2 : b1;
    float acc = 0.f;
#pragma unroll 4
    for (int k = 0; k < CS; ++k)
        acc += sn_lds[wave][k] * W[k * CH + c];
    const float m = (float)mask[row];
    const float outv = (acc + Bv[c]) * m;
    (half ? b : a)[row * CH + c] = outv;
}

// ---------------------------------------------------------------------------
// Kernel 2: T[j][c][z] = sum_e b[j][e] * w_out[(c*CH+e)*CZ + z]  (8 MB in ws).
// Spill-free: each thread owns ONE (c,z) pair, w[32] in 32 VGPRs, loops over
// a 64-row j-chunk staged in LDS. grid = 8 slices x 8 j-groups.
// ---------------------------------------------------------------------------
__global__ __launch_bounds__(512) void k_T(
    const float* __restrict__ b, const float* __restrict__ w_out,
    float* __restrict__ T)
{
    const int czg = blockIdx.x & 7;
    const int jg  = blockIdx.x >> 3;
    const int t   = threadIdx.x;
    const int idx = czg * 512 + t;
    const int c   = idx >> 7;
    const int z   = idx & (CZ - 1);

    float w[CH];
    const float* wp = w_out + (size_t)(c * CH) * CZ + z;
#pragma unroll
    for (int e = 0; e < CH; ++e) w[e] = wp[e * CZ];

    __shared__ float b_lds[64][CH];
    ((float4*)b_lds)[t] = ((const float4*)(b + (size_t)jg * 64 * CH))[t];
    __syncthreads();

    float* Tp = T + (size_t)(jg * 64) * (CH * CZ) + idx;
#pragma unroll 4
    for (int jj = 0; jj < 64; ++jj) {
        float acc = 0.f;
#pragma unroll
        for (int e = 0; e < CH; ++e) acc += b_lds[jj][e] * w[e];
        Tp[(size_t)jj * (CH * CZ)] = acc;
    }
}

// ---------------------------------------------------------------------------
// Kernel 3: z[i,j,:] = a[i,:] @ T[j,:,:] + b_out.
// Store-contiguity-first layout:
//   lane owns a z-QUAD (float4, 16 B);  lanes 0..31 -> j_even, 32..63 -> j_odd
//   => one wave store = 1 KB fully contiguous (j, j+1 adjacent in memory);
//   8 waves (j0..j0+15) in lockstep => 8 KB contiguous per block i-step.
// Nontemporal stores (round-3 vs round-4 A/B: nt is 17% faster — bypasses
// L2 dirty-line thrash for this streaming write).
// grid = 256 (8 i-tiles x 32 j-tiles), block = 512.
// T[j] quad-column in 128 VGPRs, reused 64x; a-rows broadcast from LDS.
// ---------------------------------------------------------------------------
__global__ __launch_bounds__(512, 1) void k_main(
    const float* __restrict__ a, const float* __restrict__ T,
    const float* __restrict__ b_out, float* __restrict__ out)
{
    __shared__ float a_lds[64][CH];    // 8 KB

    const int bid  = blockIdx.x;
    const int j0   = (bid & 31) * 16;  // j-tile of 16
    const int i0   = (bid >> 5) * 64;  // i-tile of 64
    const int t    = threadIdx.x;
    const int wave = t >> 6;
    const int lane = t & 63;
    const int half = lane >> 5;        // 0: even j, 1: odd j
    const int lz   = lane & 31;        // z-quad index (z = 4*lz)
    const int j    = j0 + 2 * wave + half;

    // Stage a-tile: 2048 floats, 512 threads x float4.
    ((float4*)a_lds)[t] = ((const float4*)(a + (size_t)i0 * CH))[t];

    // T[j] quad-column for this lane: 128 VGPRs.
    f4 T4[CH];
    const f4* Tj = (const f4*)(T + (size_t)j * (CH * CZ)) + lz;
#pragma unroll
    for (int c = 0; c < CH; ++c)
        T4[c] = Tj[c * (CZ / 4)];

    const f4 bo = ((const f4*)b_out)[lz];
    float* op = out + (size_t)i0 * (L * CZ) + (size_t)j * CZ + 4 * lz;

    __syncthreads();

#pragma unroll 2
    for (int ii = 0; ii < 64; ++ii) {
        const f4* ap = (const f4*)&a_lds[ii][0];
        f4 acc = bo;
#pragma unroll
        for (int q = 0; q < 8; ++q) {
            const f4 r = ap[q];
            acc += r.x * T4[4 * q + 0];
            acc += r.y * T4[4 * q + 1];
            acc += r.z * T4[4 * q + 2];
            acc += r.w * T4[4 * q + 3];
        }
        __builtin_nontemporal_store(acc, (f4*)(op + (size_t)ii * (L * CZ)));
    }
}

// ---------------------------------------------------------------------------
extern "C" void kernel_launch(void* const* d_in, const int* in_sizes, int n_in,
                              void* d_out, int out_size, void* d_ws, size_t ws_size,
                              hipStream_t stream) {
    const float* s        = (const float*)d_in[0];
    const int*   mask     = (const int*)d_in[1];
    const float* ln_scale = (const float*)d_in[2];
    const float* ln_bias  = (const float*)d_in[3];
    const float* w1       = (const float*)d_in[4];
    const float* b1       = (const float*)d_in[5];
    const float* w2       = (const float*)d_in[6];
    const float* b2       = (const float*)d_in[7];
    const float* w_out    = (const float*)d_in[8];
    const float* b_out    = (const float*)d_in[9];
    float* out = (float*)d_out;

    // Workspace: a [512*32], b [512*32], T [512*32*128]  (8.125 MB total).
    float* a = (float*)d_ws;
    float* b = a + L * CH;
    float* T = b + L * CH;

    k_ln_proj<<<L / 4, 256, 0, stream>>>(s, mask, ln_scale, ln_bias,
                                         w1, b1, w2, b2, a, b);
    k_T<<<L / 8, 512, 0, stream>>>(b, w_out, T);
    k_main<<<256, 512, 0, stream>>>(a, T, b_out, out);
}

// Round 6
// 88.612 us; speedup vs baseline: 1.1481x; 1.0053x over previous
//
#include <hip/hip_runtime.h>

// Problem constants (fixed by setup_inputs).
constexpr int L  = 512;   // sequence length
constexpr int CS = 384;   // c_s
constexpr int CH = 32;    // c_h
constexpr int CZ = 128;   // c_z
constexpr float LN_EPS = 1e-5f;

typedef float f4 __attribute__((ext_vector_type(4)));

// ---------------------------------------------------------------------------
// Kernel 1: LayerNorm over c_s + dual projection (w1/b1, w2/b2) + mask.
// ---------------------------------------------------------------------------
__global__ __launch_bounds__(256) void k_ln_proj(
    const float* __restrict__ s, const int* __restrict__ mask,
    const float* __restrict__ ln_scale, const float* __restrict__ ln_bias,
    const float* __restrict__ w1, const float* __restrict__ b1,
    const float* __restrict__ w2, const float* __restrict__ b2,
    float* __restrict__ a, float* __restrict__ b)
{
    __shared__ float sn_lds[4][CS];
    const int wave = threadIdx.x >> 6;
    const int lane = threadIdx.x & 63;
    const int row  = blockIdx.x * 4 + wave;

    const float* srow = s + row * CS;
    float v[6];
    float sum = 0.f, sumsq = 0.f;
#pragma unroll
    for (int q = 0; q < 6; ++q) {
        v[q] = srow[lane + 64 * q];
        sum   += v[q];
        sumsq += v[q] * v[q];
    }
#pragma unroll
    for (int off = 32; off; off >>= 1) {
        sum   += __shfl_xor(sum, off);
        sumsq += __shfl_xor(sumsq, off);
    }
    const float mu   = sum * (1.f / CS);
    const float var  = sumsq * (1.f / CS) - mu * mu;
    const float rstd = rsqrtf(var + LN_EPS);
#pragma unroll
    for (int q = 0; q < 6; ++q) {
        const int k = lane + 64 * q;
        sn_lds[wave][k] = (v[q] - mu) * rstd * ln_scale[k] + ln_bias[k];
    }
    __syncthreads();

    const int c    = lane & 31;
    const int half = lane >> 5;
    const float* W  = half ? w2 : w1;
    const float* Bv = half ? b2 : b1;
    float acc = 0.f;
#pragma unroll 4
    for (int k = 0; k < CS; ++k)
        acc += sn_lds[wave][k] * W[k * CH + c];
    const float m = (float)mask[row];
    const float outv = (acc + Bv[c]) * m;
    (half ? b : a)[row * CH + c] = outv;
}

// ---------------------------------------------------------------------------
// Kernel 2: T[j][c][z] = sum_e b[j][e] * w_out[(c*CH+e)*CZ + z]  (8 MB in ws).
// ---------------------------------------------------------------------------
__global__ __launch_bounds__(512) void k_T(
    const float* __restrict__ b, const float* __restrict__ w_out,
    float* __restrict__ T)
{
    const int czg = blockIdx.x & 7;
    const int jg  = blockIdx.x >> 3;
    const int t   = threadIdx.x;
    const int idx = czg * 512 + t;
    const int c   = idx >> 7;
    const int z   = idx & (CZ - 1);

    float w[CH];
    const float* wp = w_out + (size_t)(c * CH) * CZ + z;
#pragma unroll
    for (int e = 0; e < CH; ++e) w[e] = wp[e * CZ];

    __shared__ float b_lds[64][CH];
    ((float4*)b_lds)[t] = ((const float4*)(b + (size_t)jg * 64 * CH))[t];
    __syncthreads();

    float* Tp = T + (size_t)(jg * 64) * (CH * CZ) + idx;
#pragma unroll 4
    for (int jj = 0; jj < 64; ++jj) {
        float acc = 0.f;
#pragma unroll
        for (int e = 0; e < CH; ++e) acc += b_lds[jj][e] * w[e];
        Tp[(size_t)jj * (CH * CZ)] = acc;
    }
}

// ---------------------------------------------------------------------------
// Kernel 3 (A/B probe): z[i,j,:] = a[i,:] @ T[j,:,:] + b_out.
// R5 layout: lane owns a z-quad; wave covers j-pair; 8 waves = 16 j's;
// block-step writes 8 KB contiguous. NEW: raw s_barrier per i-step enforces
// wave lockstep (NOT __syncthreads — that drains vmcnt(0) per step and
// would serialize on store completion).
// MODE 0 = nontemporal store, MODE 1 = plain store.
// Each dispatch handles i-steps [II0, II1) of the 64-row i-tile -> two
// dispatches (nt half / plain half) give a within-run A/B of the store path.
// ---------------------------------------------------------------------------
template<int MODE, int II0, int II1>
__global__ __launch_bounds__(512) void k_main_t(
    const float* __restrict__ a, const float* __restrict__ T,
    const float* __restrict__ b_out, float* __restrict__ out)
{
    __shared__ float a_lds[64][CH];    // 8 KB

    const int bid  = blockIdx.x;
    const int j0   = (bid & 31) * 16;  // j-tile of 16
    const int i0   = (bid >> 5) * 64;  // i-tile of 64
    const int t    = threadIdx.x;
    const int wave = t >> 6;
    const int lane = t & 63;
    const int half = lane >> 5;        // 0: even j, 1: odd j
    const int lz   = lane & 31;        // z-quad index (z = 4*lz)
    const int j    = j0 + 2 * wave + half;

    // Stage full a-tile (both halves read their rows from it).
    ((float4*)a_lds)[t] = ((const float4*)(a + (size_t)i0 * CH))[t];

    // T[j] quad-column for this lane: 128 VGPRs.
    f4 T4[CH];
    const f4* Tj = (const f4*)(T + (size_t)j * (CH * CZ)) + lz;
#pragma unroll
    for (int c = 0; c < CH; ++c)
        T4[c] = Tj[c * (CZ / 4)];

    const f4 bo = ((const f4*)b_out)[lz];
    float* op = out + (size_t)i0 * (L * CZ) + (size_t)j * CZ + 4 * lz;

    __syncthreads();

    for (int ii = II0; ii < II1; ++ii) {
        __builtin_amdgcn_s_barrier();   // lockstep only; no vmcnt drain
        const f4* ap = (const f4*)&a_lds[ii][0];
        f4 acc = bo;
#pragma unroll
        for (int q = 0; q < 8; ++q) {
            const f4 r = ap[q];
            acc += r.x * T4[4 * q + 0];
            acc += r.y * T4[4 * q + 1];
            acc += r.z * T4[4 * q + 2];
            acc += r.w * T4[4 * q + 3];
        }
        f4* dst = (f4*)(op + (size_t)ii * (L * CZ));
        if (MODE == 0) __builtin_nontemporal_store(acc, dst);
        else           *dst = acc;
    }
}

// ---------------------------------------------------------------------------
extern "C" void kernel_launch(void* const* d_in, const int* in_sizes, int n_in,
                              void* d_out, int out_size, void* d_ws, size_t ws_size,
                              hipStream_t stream) {
    const float* s        = (const float*)d_in[0];
    const int*   mask     = (const int*)d_in[1];
    const float* ln_scale = (const float*)d_in[2];
    const float* ln_bias  = (const float*)d_in[3];
    const float* w1       = (const float*)d_in[4];
    const float* b1       = (const float*)d_in[5];
    const float* w2       = (const float*)d_in[6];
    const float* b2       = (const float*)d_in[7];
    const float* w_out    = (const float*)d_in[8];
    const float* b_out    = (const float*)d_in[9];
    float* out = (float*)d_out;

    // Workspace: a [512*32], b [512*32], T [512*32*128]  (8.125 MB total).
    float* a = (float*)d_ws;
    float* b = a + L * CH;
    float* T = b + L * CH;

    k_ln_proj<<<L / 4, 256, 0, stream>>>(s, mask, ln_scale, ln_bias,
                                         w1, b1, w2, b2, a, b);
    k_T<<<L / 8, 512, 0, stream>>>(b, w_out, T);
    // A/B: nt stores for i-steps [0,32), plain stores for [32,64).
    k_main_t<0, 0, 32><<<256, 512, 0, stream>>>(a, T, b_out, out);
    k_main_t<1, 32, 64><<<256, 512, 0, stream>>>(a, T, b_out, out);
}